// Round 3
// baseline (103.323 us; speedup 1.0000x reference)
//
#include <hip/hip_runtime.h>

#define N_NODES 2048
#define F_IN 64
#define C_OUT 8
#define H_HID 32
#define G_NUM 16

// ---------------------------------------------------------------------------
// Kernel 1 (fused): blocks [0,256): fsum for 8 nodes each (512 thr = 8 waves,
// lane = feature f). Blocks [256,260): parallel graph-boundary detection.
//
// fsum[n,c] = sum_f ( relu(x[n,f]*W1[f,:]+b1[f,:]) . W2[f,c,:] + b2[f,c] )
//
// W2 staged in LDS, layout sW2[(h<<9) + ((f^h)<<3) + c]:
//  - staging: global read coalesced (e = tid + 512k), write banks spread
//  - compute: per (h) lane f reads an 8-float slot (f^h) -> slots are a
//    permutation of 0..63 across lanes -> conflict-free float4 reads
// ---------------------------------------------------------------------------
__global__ __launch_bounds__(512, 4) void fsum_bounds_kernel(
    const float* __restrict__ x, const float* __restrict__ W1,
    const float* __restrict__ b1, const float* __restrict__ W2,
    const float* __restrict__ b2, float* __restrict__ fsum,
    const int* __restrict__ batch, int* __restrict__ starts)
{
    const int tid = threadIdx.x;

    if (blockIdx.x >= 256) {
        // ----- bounds part -----
        const int i = (blockIdx.x - 256) * 512 + tid;
        if (i < N_NODES) {
            const int cur = batch[i];
            const int prev = (i == 0) ? -1 : batch[i - 1];
            for (int g = prev + 1; g <= cur; ++g) starts[g] = i;
            if (i == N_NODES - 1)
                for (int g = cur + 1; g <= G_NUM; ++g) starts[g] = N_NODES;
        }
        return;
    }

    // ----- fsum part -----
    __shared__ float sW2[F_IN * C_OUT * H_HID];   // 16384 floats = 64 KB

    // stage W2: coalesced global read, swizzled LDS write
    #pragma unroll
    for (int k = 0; k < 32; ++k) {
        const int e = tid + k * 512;              // e = ((f*8+c)*32+h)
        const float v = W2[e];
        const int h = e & 31;
        const int c = (e >> 5) & 7;
        const int f = e >> 8;
        sW2[(h << 9) + ((f ^ h) << 3) + c] = v;
    }

    const int wv = tid >> 6;        // wave = local node
    const int f  = tid & 63;        // lane = feature
    const int n  = blockIdx.x * 8 + wv;

    // preload W1/b1 rows into registers (16 float4 loads)
    float w1r[H_HID], b1r[H_HID];
    #pragma unroll
    for (int k = 0; k < 8; ++k) {
        *(float4*)&w1r[k * 4] = *(const float4*)&W1[f * H_HID + k * 4];
        *(float4*)&b1r[k * 4] = *(const float4*)&b1[f * H_HID + k * 4];
    }

    const float xv = x[n * F_IN + f];
    float4 acc0 = *(const float4*)&b2[f * C_OUT];
    float4 acc1 = *(const float4*)&b2[f * C_OUT + 4];

    __syncthreads();

    #pragma unroll
    for (int h = 0; h < H_HID; ++h) {
        float hv = xv * w1r[h] + b1r[h];
        hv = hv > 0.0f ? hv : 0.0f;
        const int idx = (h << 9) + ((f ^ h) << 3);
        const float4 lo = *(const float4*)&sW2[idx];
        const float4 hi = *(const float4*)&sW2[idx + 4];
        acc0.x += hv * lo.x; acc0.y += hv * lo.y;
        acc0.z += hv * lo.z; acc0.w += hv * lo.w;
        acc1.x += hv * hi.x; acc1.y += hv * hi.y;
        acc1.z += hv * hi.z; acc1.w += hv * hi.w;
    }

    // wave64 reduce over features
    float a[C_OUT] = {acc0.x, acc0.y, acc0.z, acc0.w, acc1.x, acc1.y, acc1.z, acc1.w};
    #pragma unroll
    for (int c = 0; c < C_OUT; ++c) {
        float v = a[c];
        for (int off = 32; off; off >>= 1) v += __shfl_down(v, off);
        if (f == 0) fsum[n * C_OUT + c] = v;
    }
}

// ---------------------------------------------------------------------------
// Kernel 2: per-row i: rowout[i,c] = sum_{j in graph(i)} rho(i,j,c)/norm * fsum[j,c]
// Weight LDS reads are uniform-address (broadcast) -> conflict-free.
// ---------------------------------------------------------------------------
__global__ __launch_bounds__(128) void row_kernel(
    const float* __restrict__ dist, const float* __restrict__ norm,
    const int* __restrict__ batch, const int* __restrict__ starts,
    const float* __restrict__ rW1, const float* __restrict__ rb1,
    const float* __restrict__ rW2, const float* __restrict__ rb2,
    const float* __restrict__ fsum, float* __restrict__ rowout)
{
    const int i = blockIdx.x;
    const int tid = threadIdx.x;
    const int g = batch[i];
    const int js = starts[g];
    const int je = starts[g + 1];

    __shared__ float sW1[H_HID], sb1[H_HID], sW2[C_OUT * H_HID], sb2[C_OUT];
    if (tid < H_HID) { sW1[tid] = rW1[tid]; sb1[tid] = rb1[tid]; }
    if (tid < C_OUT) sb2[tid] = rb2[tid];
    for (int k = tid; k < C_OUT * H_HID; k += 128) sW2[k] = rW2[k];
    __syncthreads();

    float acc[C_OUT] = {0.f, 0.f, 0.f, 0.f, 0.f, 0.f, 0.f, 0.f};

    for (int j = js + tid; j < je; j += 128) {
        const float d  = dist[(long)i * N_NODES + j];
        const float s  = 1.0f / (1.0f + d);
        const float nv = norm[(long)i * N_NODES + j];
        const float invn = (nv == 0.0f) ? 1.0f : (1.0f / nv);

        float rho[C_OUT];
        #pragma unroll
        for (int c = 0; c < C_OUT; ++c) rho[c] = sb2[c];

        #pragma unroll
        for (int h = 0; h < H_HID; ++h) {
            float rh = s * sW1[h] + sb1[h];
            rh = rh > 0.0f ? rh : 0.0f;
            #pragma unroll
            for (int c = 0; c < C_OUT; ++c) rho[c] += rh * sW2[c * H_HID + h];
        }

        const float4 f0 = *(const float4*)&fsum[j * C_OUT];
        const float4 f1 = *(const float4*)&fsum[j * C_OUT + 4];
        acc[0] += rho[0] * invn * f0.x;
        acc[1] += rho[1] * invn * f0.y;
        acc[2] += rho[2] * invn * f0.z;
        acc[3] += rho[3] * invn * f0.w;
        acc[4] += rho[4] * invn * f1.x;
        acc[5] += rho[5] * invn * f1.y;
        acc[6] += rho[6] * invn * f1.z;
        acc[7] += rho[7] * invn * f1.w;
    }

    __shared__ float red[2][C_OUT];
    const int lane = tid & 63, wv = tid >> 6;
    #pragma unroll
    for (int c = 0; c < C_OUT; ++c) {
        float v = acc[c];
        for (int off = 32; off; off >>= 1) v += __shfl_down(v, off);
        if (lane == 0) red[wv][c] = v;
    }
    __syncthreads();
    if (tid < C_OUT) rowout[i * C_OUT + tid] = red[0][tid] + red[1][tid];
}

// ---------------------------------------------------------------------------
// Kernel 3: graph readout (deterministic ordered sum)
// ---------------------------------------------------------------------------
__global__ __launch_bounds__(64) void readout_kernel(
    const float* __restrict__ rowout, const int* __restrict__ starts,
    float* __restrict__ out)
{
    const int g = blockIdx.x;
    const int tid = threadIdx.x;
    const int is = starts[g];
    const int ie = starts[g + 1];

    float acc[C_OUT] = {0.f, 0.f, 0.f, 0.f, 0.f, 0.f, 0.f, 0.f};
    for (int i = is + tid; i < ie; i += 64) {
        const float4 f0 = *(const float4*)&rowout[i * C_OUT];
        const float4 f1 = *(const float4*)&rowout[i * C_OUT + 4];
        acc[0] += f0.x; acc[1] += f0.y; acc[2] += f0.z; acc[3] += f0.w;
        acc[4] += f1.x; acc[5] += f1.y; acc[6] += f1.z; acc[7] += f1.w;
    }

    #pragma unroll
    for (int c = 0; c < C_OUT; ++c) {
        float v = acc[c];
        for (int off = 32; off; off >>= 1) v += __shfl_down(v, off);
        if (tid == 0) out[g * C_OUT + c] = v;
    }
}

extern "C" void kernel_launch(void* const* d_in, const int* in_sizes, int n_in,
                              void* d_out, int out_size, void* d_ws, size_t ws_size,
                              hipStream_t stream)
{
    const float* x    = (const float*)d_in[0];
    const float* dist = (const float*)d_in[1];
    const float* norm = (const float*)d_in[2];
    const int*   batch= (const int*)d_in[3];
    const float* fsW1 = (const float*)d_in[4];
    const float* fsb1 = (const float*)d_in[5];
    const float* fsW2 = (const float*)d_in[6];
    const float* fsb2 = (const float*)d_in[7];
    const float* rW1  = (const float*)d_in[8];
    const float* rb1  = (const float*)d_in[9];
    const float* rW2  = (const float*)d_in[10];
    const float* rb2  = (const float*)d_in[11];
    float* out = (float*)d_out;

    float* fsum   = (float*)d_ws;                       // N*C floats
    float* rowout = fsum + N_NODES * C_OUT;             // N*C floats
    int*   starts = (int*)(rowout + N_NODES * C_OUT);   // G+1 ints

    fsum_bounds_kernel<<<260, 512, 0, stream>>>(x, fsW1, fsb1, fsW2, fsb2,
                                                fsum, batch, starts);
    row_kernel<<<N_NODES, 128, 0, stream>>>(dist, norm, batch, starts,
                                            rW1, rb1, rW2, rb2, fsum, rowout);
    readout_kernel<<<G_NUM, 64, 0, stream>>>(rowout, starts, out);
}

// Round 4
// 70.503 us; speedup vs baseline: 1.4655x; 1.4655x over previous
//
#include <hip/hip_runtime.h>

#define N_NODES 2048
#define F_IN 64
#define C_OUT 8
#define H_HID 32
#define G_NUM 16

// ---------------------------------------------------------------------------
// Kernel 1 (fused): blocks [0,32): fsum for 64 nodes each (256 thr = 4 waves).
// Block 32: parallel graph-boundary detection.
//
// fsum[n,c] = sum_f ( relu(x[n,f]*W1[f,:]+b1[f,:]) . W2[f,c,:] + b2[f,c] )
//
// Parallelization: lane = node (64 nodes/block), wave = 16-feature slice.
// Weight addresses are wave-uniform -> one cache line per load (broadcast),
// no divergence, no per-thread weight arrays (no spill risk).
// x staged in LDS [64][65] (padded: lane*65 -> conflict-free column reads).
// ---------------------------------------------------------------------------
__global__ __launch_bounds__(256) void fsum_bounds_kernel(
    const float* __restrict__ x, const float* __restrict__ W1,
    const float* __restrict__ b1, const float* __restrict__ W2,
    const float* __restrict__ b2, float* __restrict__ fsum,
    const int* __restrict__ batch, int* __restrict__ starts)
{
    const int tid = threadIdx.x;

    if (blockIdx.x >= 32) {
        // ----- bounds part: starts[g] = first i with batch[i] >= g -----
        for (int i = tid; i < N_NODES; i += 256) {
            const int cur = batch[i];
            const int prev = (i == 0) ? -1 : batch[i - 1];
            for (int g = prev + 1; g <= cur; ++g) starts[g] = i;
            if (i == N_NODES - 1)
                for (int g = cur + 1; g <= G_NUM; ++g) starts[g] = N_NODES;
        }
        return;
    }

    __shared__ float sx[64 * 65];          // padded x tile, 16.6 KB
    __shared__ float red[4 * 64 * 9];      // padded partials, 9.2 KB

    const int n0 = blockIdx.x * 64;

    // stage x tile: contiguous 16 KB, fully coalesced
    #pragma unroll
    for (int k = 0; k < 16; ++k) {
        const int e = tid + k * 256;       // e = n_local*64 + f
        sx[(e >> 6) * 65 + (e & 63)] = x[n0 * F_IN + e];
    }
    __syncthreads();

    const int wv   = tid >> 6;             // wave -> feature slice
    const int lane = tid & 63;             // lane -> local node
    const int fbase = wv * 16;

    float acc[C_OUT] = {0.f, 0.f, 0.f, 0.f, 0.f, 0.f, 0.f, 0.f};

    for (int fi = 0; fi < 16; ++fi) {
        const int f = fbase + fi;
        const float xv = sx[lane * 65 + f];

        // layer 1: rh[h] = relu(xv*W1[f,h] + b1[f,h]); uniform-address loads
        float rh[H_HID];
        #pragma unroll
        for (int k = 0; k < 8; ++k) {
            const float4 w = *(const float4*)&W1[f * H_HID + k * 4];
            const float4 bb = *(const float4*)&b1[f * H_HID + k * 4];
            float v0 = xv * w.x + bb.x; rh[k*4+0] = v0 > 0.f ? v0 : 0.f;
            float v1 = xv * w.y + bb.y; rh[k*4+1] = v1 > 0.f ? v1 : 0.f;
            float v2 = xv * w.z + bb.z; rh[k*4+2] = v2 > 0.f ? v2 : 0.f;
            float v3 = xv * w.w + bb.w; rh[k*4+3] = v3 > 0.f ? v3 : 0.f;
        }

        // layer 2: acc[c] += rh . W2[f,c,:]  (contiguous uniform loads)
        #pragma unroll
        for (int c = 0; c < C_OUT; ++c) {
            const float* w2row = &W2[(f * C_OUT + c) * H_HID];
            float s = 0.f;
            #pragma unroll
            for (int k = 0; k < 8; ++k) {
                const float4 w = *(const float4*)&w2row[k * 4];
                s += rh[k*4+0] * w.x + rh[k*4+1] * w.y
                   + rh[k*4+2] * w.z + rh[k*4+3] * w.w;
            }
            acc[c] += s + ((c == 0) ? 0.f : 0.f);
        }
        // bias b2[f,c] (uniform loads, add once per f)
        const float4 bb0 = *(const float4*)&b2[f * C_OUT];
        const float4 bb1 = *(const float4*)&b2[f * C_OUT + 4];
        acc[0] += bb0.x; acc[1] += bb0.y; acc[2] += bb0.z; acc[3] += bb0.w;
        acc[4] += bb1.x; acc[5] += bb1.y; acc[6] += bb1.z; acc[7] += bb1.w;
    }

    // cross-wave combine via padded LDS
    #pragma unroll
    for (int c = 0; c < C_OUT; ++c)
        red[wv * 576 + lane * 9 + c] = acc[c];
    __syncthreads();

    // 512 (n,c) pairs, 256 threads -> 2 each
    #pragma unroll
    for (int p = tid; p < 512; p += 256) {
        const int nl = p >> 3, c = p & 7;
        float v = red[0 * 576 + nl * 9 + c] + red[1 * 576 + nl * 9 + c]
                + red[2 * 576 + nl * 9 + c] + red[3 * 576 + nl * 9 + c];
        fsum[(n0 + nl) * C_OUT + c] = v;
    }
}

// ---------------------------------------------------------------------------
// Kernel 2: 4 rows per block (wave = row). rowout[i,c] =
//   sum_{j in graph(i)} (rho(i,j,c)/norm_safe) * fsum[j,c]
// ---------------------------------------------------------------------------
__global__ __launch_bounds__(256) void row_kernel(
    const float* __restrict__ dist, const float* __restrict__ norm,
    const int* __restrict__ batch, const int* __restrict__ starts,
    const float* __restrict__ rW1, const float* __restrict__ rb1,
    const float* __restrict__ rW2, const float* __restrict__ rb2,
    const float* __restrict__ fsum, float* __restrict__ rowout)
{
    const int tid = threadIdx.x;

    __shared__ float sW1[H_HID], sb1[H_HID], sW2[C_OUT * H_HID], sb2[C_OUT];
    if (tid < H_HID) { sW1[tid] = rW1[tid]; sb1[tid] = rb1[tid]; }
    if (tid >= 64 && tid < 64 + C_OUT) sb2[tid - 64] = rb2[tid - 64];
    if (tid >= 128) { const int k = tid - 128;
        sW2[k] = rW2[k]; sW2[k + 128] = rW2[k + 128]; }
    __syncthreads();

    const int wv = tid >> 6, lane = tid & 63;
    const int i = blockIdx.x * 4 + wv;
    const int g = batch[i];
    const int js = starts[g];
    const int je = starts[g + 1];

    float acc[C_OUT] = {0.f, 0.f, 0.f, 0.f, 0.f, 0.f, 0.f, 0.f};

    for (int j = js + lane; j < je; j += 64) {
        const float d  = dist[i * N_NODES + j];
        const float s  = 1.0f / (1.0f + d);
        const float nv = norm[i * N_NODES + j];
        const float invn = (nv == 0.0f) ? 1.0f : (1.0f / nv);

        float rho[C_OUT];
        #pragma unroll
        for (int c = 0; c < C_OUT; ++c) rho[c] = sb2[c];

        #pragma unroll
        for (int h = 0; h < H_HID; ++h) {
            float rh = s * sW1[h] + sb1[h];
            rh = rh > 0.0f ? rh : 0.0f;
            #pragma unroll
            for (int c = 0; c < C_OUT; ++c) rho[c] += rh * sW2[c * H_HID + h];
        }

        const float4 f0 = *(const float4*)&fsum[j * C_OUT];
        const float4 f1 = *(const float4*)&fsum[j * C_OUT + 4];
        acc[0] += rho[0] * invn * f0.x;
        acc[1] += rho[1] * invn * f0.y;
        acc[2] += rho[2] * invn * f0.z;
        acc[3] += rho[3] * invn * f0.w;
        acc[4] += rho[4] * invn * f1.x;
        acc[5] += rho[5] * invn * f1.y;
        acc[6] += rho[6] * invn * f1.z;
        acc[7] += rho[7] * invn * f1.w;
    }

    // per-wave shuffle reduce; lane 0 writes its row
    #pragma unroll
    for (int c = 0; c < C_OUT; ++c) {
        float v = acc[c];
        for (int off = 32; off; off >>= 1) v += __shfl_down(v, off);
        acc[c] = v;
    }
    if (lane == 0) {
        float4 o0 = {acc[0], acc[1], acc[2], acc[3]};
        float4 o1 = {acc[4], acc[5], acc[6], acc[7]};
        *(float4*)&rowout[i * C_OUT] = o0;
        *(float4*)&rowout[i * C_OUT + 4] = o1;
    }
}

// ---------------------------------------------------------------------------
// Kernel 3: graph readout (deterministic ordered sum)
// ---------------------------------------------------------------------------
__global__ __launch_bounds__(64) void readout_kernel(
    const float* __restrict__ rowout, const int* __restrict__ starts,
    float* __restrict__ out)
{
    const int g = blockIdx.x;
    const int tid = threadIdx.x;
    const int is = starts[g];
    const int ie = starts[g + 1];

    float acc[C_OUT] = {0.f, 0.f, 0.f, 0.f, 0.f, 0.f, 0.f, 0.f};
    for (int i = is + tid; i < ie; i += 64) {
        const float4 f0 = *(const float4*)&rowout[i * C_OUT];
        const float4 f1 = *(const float4*)&rowout[i * C_OUT + 4];
        acc[0] += f0.x; acc[1] += f0.y; acc[2] += f0.z; acc[3] += f0.w;
        acc[4] += f1.x; acc[5] += f1.y; acc[6] += f1.z; acc[7] += f1.w;
    }

    #pragma unroll
    for (int c = 0; c < C_OUT; ++c) {
        float v = acc[c];
        for (int off = 32; off; off >>= 1) v += __shfl_down(v, off);
        if (tid == 0) out[g * C_OUT + c] = v;
    }
}

extern "C" void kernel_launch(void* const* d_in, const int* in_sizes, int n_in,
                              void* d_out, int out_size, void* d_ws, size_t ws_size,
                              hipStream_t stream)
{
    const float* x    = (const float*)d_in[0];
    const float* dist = (const float*)d_in[1];
    const float* norm = (const float*)d_in[2];
    const int*   batch= (const int*)d_in[3];
    const float* fsW1 = (const float*)d_in[4];
    const float* fsb1 = (const float*)d_in[5];
    const float* fsW2 = (const float*)d_in[6];
    const float* fsb2 = (const float*)d_in[7];
    const float* rW1  = (const float*)d_in[8];
    const float* rb1  = (const float*)d_in[9];
    const float* rW2  = (const float*)d_in[10];
    const float* rb2  = (const float*)d_in[11];
    float* out = (float*)d_out;

    float* fsum   = (float*)d_ws;                       // N*C floats
    float* rowout = fsum + N_NODES * C_OUT;             // N*C floats
    int*   starts = (int*)(rowout + N_NODES * C_OUT);   // G+1 ints

    fsum_bounds_kernel<<<33, 256, 0, stream>>>(x, fsW1, fsb1, fsW2, fsb2,
                                               fsum, batch, starts);
    row_kernel<<<N_NODES / 4, 256, 0, stream>>>(dist, norm, batch, starts,
                                                rW1, rb1, rW2, rb2, fsum, rowout);
    readout_kernel<<<G_NUM, 64, 0, stream>>>(rowout, starts, out);
}

// Round 5
// 30.071 us; speedup vs baseline: 3.4360x; 2.3446x over previous
//
#include <hip/hip_runtime.h>

#define N_NODES 2048
#define F_IN 64
#define C_OUT 8
#define H_HID 32
#define G_NUM 16

// ---------------------------------------------------------------------------
// Kernel 1 (fused): blocks [0,256): fsum for 8 nodes each (512 thr = 8 waves,
// wave = node, lane = feature). Block 256: graph-boundary detection.
//
// fsum[n,c] = sum_f ( relu(x[n,f]*W1[f,:]+b1[f,:]) . W2[f,c,:] + b2[f,c] )
//
// Weights live in LDS/registers:
//  - W1/b1 transposed [h][f] via LDS, preloaded to regs (static index, 64 VGPR)
//  - W2 as two float4 arrays sA/sB[h*64+f]: lane f reads consecutive 16B ->
//    bank-optimal ds_read_b128 (8-cyc minimum, zero conflicts)
// ---------------------------------------------------------------------------
__global__ __launch_bounds__(512) void fsum_bounds_kernel(
    const float* __restrict__ x, const float* __restrict__ W1,
    const float* __restrict__ b1, const float* __restrict__ W2,
    const float* __restrict__ b2, float* __restrict__ fsum,
    const int* __restrict__ batch, int* __restrict__ starts)
{
    const int tid = threadIdx.x;

    if (blockIdx.x >= 256) {
        for (int i = tid; i < N_NODES; i += 512) {
            const int cur = batch[i];
            const int prev = (i == 0) ? -1 : batch[i - 1];
            for (int g = prev + 1; g <= cur; ++g) starts[g] = i;
            if (i == N_NODES - 1)
                for (int g = cur + 1; g <= G_NUM; ++g) starts[g] = N_NODES;
        }
        return;
    }

    __shared__ float4 sA[H_HID * F_IN];   // 32 KB: W2[f][c<4][h]  -> [h][f].c
    __shared__ float4 sB[H_HID * F_IN];   // 32 KB: W2[f][c>=4][h] -> [h][f].c
    float* tmp = (float*)sA;              // transient W1T/b1T staging (16 KB)

    // phase 1: transpose W1,b1 -> tmp[h*64+f], tmp[2048+h*64+f]
    #pragma unroll
    for (int k = 0; k < 4; ++k) {
        const int e = tid + k * 512;      // e = f*32 + h
        const int f_ = e >> 5, h_ = e & 31;
        tmp[h_ * 64 + f_]        = W1[e];
        tmp[2048 + h_ * 64 + f_] = b1[e];
    }
    __syncthreads();

    // phase 2: per-lane register preload of W1/b1 rows (conflict-free b32)
    const int wv = tid >> 6;              // wave -> local node
    const int f  = tid & 63;              // lane -> feature
    float w1r[H_HID], b1r[H_HID];
    #pragma unroll
    for (int h = 0; h < H_HID; ++h) {
        w1r[h] = tmp[h * 64 + f];
        b1r[h] = tmp[2048 + h * 64 + f];
    }
    __syncthreads();

    // phase 3: stage W2 (coalesced read, transposed b32 writes)
    #pragma unroll
    for (int k = 0; k < 8; ++k) {
        const int eb = 4 * (tid + k * 512);   // = (f*8+c)*32 + h0, h0%4==0
        const float4 v = *(const float4*)&W2[eb];
        const int h0 = eb & 31;
        const int c  = (eb >> 5) & 7;
        const int ff = eb >> 8;
        float* dst = (c < 4) ? (float*)sA : (float*)sB;
        const int cc = c & 3;
        dst[(h0 + 0) * 256 + ff * 4 + cc] = v.x;
        dst[(h0 + 1) * 256 + ff * 4 + cc] = v.y;
        dst[(h0 + 2) * 256 + ff * 4 + cc] = v.z;
        dst[(h0 + 3) * 256 + ff * 4 + cc] = v.w;
    }
    __syncthreads();

    // compute
    const int n = blockIdx.x * 8 + wv;
    const float xv = x[n * F_IN + f];
    const float4 b2lo = *(const float4*)&b2[f * C_OUT];
    const float4 b2hi = *(const float4*)&b2[f * C_OUT + 4];

    float4 acc0 = {0.f, 0.f, 0.f, 0.f};
    float4 acc1 = {0.f, 0.f, 0.f, 0.f};
    #pragma unroll
    for (int h = 0; h < H_HID; ++h) {
        float rv = fmaf(xv, w1r[h], b1r[h]);
        rv = fmaxf(rv, 0.f);
        const float4 wa = sA[h * 64 + f];
        const float4 wb = sB[h * 64 + f];
        acc0.x += rv * wa.x; acc0.y += rv * wa.y;
        acc0.z += rv * wa.z; acc0.w += rv * wa.w;
        acc1.x += rv * wb.x; acc1.y += rv * wb.y;
        acc1.z += rv * wb.z; acc1.w += rv * wb.w;
    }
    acc0.x += b2lo.x; acc0.y += b2lo.y; acc0.z += b2lo.z; acc0.w += b2lo.w;
    acc1.x += b2hi.x; acc1.y += b2hi.y; acc1.z += b2hi.z; acc1.w += b2hi.w;

    // wave64 reduce over features
    float a[C_OUT] = {acc0.x, acc0.y, acc0.z, acc0.w,
                      acc1.x, acc1.y, acc1.z, acc1.w};
    #pragma unroll
    for (int c = 0; c < C_OUT; ++c) {
        float v = a[c];
        for (int off = 32; off; off >>= 1) v += __shfl_down(v, off);
        a[c] = v;
    }
    if (f == 0) {
        float4 o0 = {a[0], a[1], a[2], a[3]};
        float4 o1 = {a[4], a[5], a[6], a[7]};
        *(float4*)&fsum[n * C_OUT] = o0;
        *(float4*)&fsum[n * C_OUT + 4] = o1;
    }
}

// ---------------------------------------------------------------------------
// Kernel 2: 4 rows per block (wave = row). rowout[i,c] =
//   sum_{j in graph(i)} (rho(i,j,c)/norm_safe) * fsum[j,c]
// ---------------------------------------------------------------------------
__global__ __launch_bounds__(256) void row_kernel(
    const float* __restrict__ dist, const float* __restrict__ norm,
    const int* __restrict__ batch, const int* __restrict__ starts,
    const float* __restrict__ rW1, const float* __restrict__ rb1,
    const float* __restrict__ rW2, const float* __restrict__ rb2,
    const float* __restrict__ fsum, float* __restrict__ rowout)
{
    const int tid = threadIdx.x;

    __shared__ float sW1[H_HID], sb1[H_HID], sW2[C_OUT * H_HID], sb2[C_OUT];
    if (tid < H_HID) { sW1[tid] = rW1[tid]; sb1[tid] = rb1[tid]; }
    if (tid >= 64 && tid < 64 + C_OUT) sb2[tid - 64] = rb2[tid - 64];
    if (tid >= 128) { const int k = tid - 128;
        sW2[k] = rW2[k]; sW2[k + 128] = rW2[k + 128]; }
    __syncthreads();

    const int wv = tid >> 6, lane = tid & 63;
    const int i = blockIdx.x * 4 + wv;
    const int g = batch[i];
    const int js = starts[g];
    const int je = starts[g + 1];

    float acc[C_OUT] = {0.f, 0.f, 0.f, 0.f, 0.f, 0.f, 0.f, 0.f};

    for (int j = js + lane; j < je; j += 64) {
        const float d  = dist[i * N_NODES + j];
        const float s  = 1.0f / (1.0f + d);
        const float nv = norm[i * N_NODES + j];
        const float invn = (nv == 0.0f) ? 1.0f : (1.0f / nv);

        float rho[C_OUT];
        #pragma unroll
        for (int c = 0; c < C_OUT; ++c) rho[c] = sb2[c];

        #pragma unroll
        for (int h = 0; h < H_HID; ++h) {
            float rh = s * sW1[h] + sb1[h];
            rh = rh > 0.0f ? rh : 0.0f;
            #pragma unroll
            for (int c = 0; c < C_OUT; ++c) rho[c] += rh * sW2[c * H_HID + h];
        }

        const float4 f0 = *(const float4*)&fsum[j * C_OUT];
        const float4 f1 = *(const float4*)&fsum[j * C_OUT + 4];
        acc[0] += rho[0] * invn * f0.x;
        acc[1] += rho[1] * invn * f0.y;
        acc[2] += rho[2] * invn * f0.z;
        acc[3] += rho[3] * invn * f0.w;
        acc[4] += rho[4] * invn * f1.x;
        acc[5] += rho[5] * invn * f1.y;
        acc[6] += rho[6] * invn * f1.z;
        acc[7] += rho[7] * invn * f1.w;
    }

    #pragma unroll
    for (int c = 0; c < C_OUT; ++c) {
        float v = acc[c];
        for (int off = 32; off; off >>= 1) v += __shfl_down(v, off);
        acc[c] = v;
    }
    if (lane == 0) {
        float4 o0 = {acc[0], acc[1], acc[2], acc[3]};
        float4 o1 = {acc[4], acc[5], acc[6], acc[7]};
        *(float4*)&rowout[i * C_OUT] = o0;
        *(float4*)&rowout[i * C_OUT + 4] = o1;
    }
}

// ---------------------------------------------------------------------------
// Kernel 3: graph readout (deterministic ordered sum)
// ---------------------------------------------------------------------------
__global__ __launch_bounds__(64) void readout_kernel(
    const float* __restrict__ rowout, const int* __restrict__ starts,
    float* __restrict__ out)
{
    const int g = blockIdx.x;
    const int tid = threadIdx.x;
    const int is = starts[g];
    const int ie = starts[g + 1];

    float acc[C_OUT] = {0.f, 0.f, 0.f, 0.f, 0.f, 0.f, 0.f, 0.f};
    for (int i = is + tid; i < ie; i += 64) {
        const float4 f0 = *(const float4*)&rowout[i * C_OUT];
        const float4 f1 = *(const float4*)&rowout[i * C_OUT + 4];
        acc[0] += f0.x; acc[1] += f0.y; acc[2] += f0.z; acc[3] += f0.w;
        acc[4] += f1.x; acc[5] += f1.y; acc[6] += f1.z; acc[7] += f1.w;
    }

    #pragma unroll
    for (int c = 0; c < C_OUT; ++c) {
        float v = acc[c];
        for (int off = 32; off; off >>= 1) v += __shfl_down(v, off);
        if (tid == 0) out[g * C_OUT + c] = v;
    }
}

extern "C" void kernel_launch(void* const* d_in, const int* in_sizes, int n_in,
                              void* d_out, int out_size, void* d_ws, size_t ws_size,
                              hipStream_t stream)
{
    const float* x    = (const float*)d_in[0];
    const float* dist = (const float*)d_in[1];
    const float* norm = (const float*)d_in[2];
    const int*   batch= (const int*)d_in[3];
    const float* fsW1 = (const float*)d_in[4];
    const float* fsb1 = (const float*)d_in[5];
    const float* fsW2 = (const float*)d_in[6];
    const float* fsb2 = (const float*)d_in[7];
    const float* rW1  = (const float*)d_in[8];
    const float* rb1  = (const float*)d_in[9];
    const float* rW2  = (const float*)d_in[10];
    const float* rb2  = (const float*)d_in[11];
    float* out = (float*)d_out;

    float* fsum   = (float*)d_ws;                       // N*C floats
    float* rowout = fsum + N_NODES * C_OUT;             // N*C floats
    int*   starts = (int*)(rowout + N_NODES * C_OUT);   // G+1 ints

    fsum_bounds_kernel<<<257, 512, 0, stream>>>(x, fsW1, fsb1, fsW2, fsb2,
                                                fsum, batch, starts);
    row_kernel<<<N_NODES / 4, 256, 0, stream>>>(dist, norm, batch, starts,
                                                rW1, rb1, rW2, rb2, fsum, rowout);
    readout_kernel<<<G_NUM, 64, 0, stream>>>(rowout, starts, out);
}